// Round 12
// baseline (389.140 us; speedup 1.0000x reference)
//
#include <hip/hip_runtime.h>
#include <cstdint>
#include <cstddef>

#define BATCH 32
#define NCLS 81
#define NFG 80
#define NBOX 15130
#define CBOX 512          // boxes per k1 block (2 per thread)
#define NCHUNK2 30        // ceil(15130/512)
#define TOPK 200
#define NTASK (BATCH * NFG)
#define NEG_INF -1e30f
#define GCAP 1024         // per-task candidate capacity (measured mean ~434)
#define SORTCAP 1024
#define LCAP 1920         // per-block survivor list; E~1180 measured-scaled, fallback below
#define SCORE_THR 0.05f
#define CRITERIA 0.45f

// ---------------------------------------------------------------- K1: decode + softmax + compacted candidate emission
// ROUND-10/11 LESSON: "fill vals[81] -> reduce" CANNOT be made register-
// resident (compiler re-loads inside the 81-deep add chain at VGPR=56-60
// no matter what launch_bounds says -> latency-bound 1.9 TB/s, 103 us).
// Restructure: three passes, each with <=18 floats live and 9+ independent
// float2 loads in flight. Sum order stays EXACT sequential c=0..80.
// Pointers laundered BETWEEN passes so CSE can't merge the load streams
// back into one 81-live array (round-2 spill / round-10 reload disease).
// ROUND-3 LESSON: no per-element global atomics on few hot addresses.
// ROUND-4/5/6 LESSON: k2 must read compacted lists, not re-stream scores.
__global__ __launch_bounds__(256) void k1_fused(
    const float* __restrict__ bboxes,   // [B,4,N]
    const float* __restrict__ scores,   // [B,C,N]
    const float* __restrict__ dboxes,   // [N,4]
    float4* __restrict__ ltrb,          // [B*N]
    unsigned long long* __restrict__ gcand,  // [NTASK*GCAP]
    int* __restrict__ gcnt)             // [NTASK] (zeroed before launch)
{
    const int blk = blockIdx.x;
    const int b = blk / NCHUNK2;
    const int chunk = blk - b * NCHUNK2;
    const int tid = threadIdx.x;
    const int n0 = chunk * CBOX + tid * 2;      // NBOX even -> pair never straddles
    const bool valid = (n0 < NBOX);

    __shared__ unsigned long long list[LCAP];   // (p_bits<<32)|(cfg<<24)|n
    __shared__ int lcnt;
    __shared__ int ccnt[NFG];
    __shared__ int cbase[NFG];

    if (tid == 0) lcnt = 0;
    if (tid < NFG) ccnt[tid] = 0;
    __syncthreads();

    const float* srow = scores + (size_t)b * NCLS * NBOX;   // image base

    float m0 = -INFINITY, m1 = -INFINITY;
    float s0 = 1.f, s1 = 1.f;
    float thr0 = 1e30f, thr1 = 1e30f;

    if (valid) {
        // ---- decode both boxes (bit-exact expressions, validated rounds 1-11)
        const float* bbp = bboxes + (size_t)b * 4 * NBOX + n0;
        float2 bx = *(const float2*)(bbp);
        float2 by = *(const float2*)(bbp + NBOX);
        float2 bw = *(const float2*)(bbp + 2 * (size_t)NBOX);
        float2 bh = *(const float2*)(bbp + 3 * (size_t)NBOX);
        float4 d0 = reinterpret_cast<const float4*>(dboxes)[n0];
        float4 d1 = reinterpret_cast<const float4*>(dboxes)[n0 + 1];
        {
            float xx = __fadd_rn(__fmul_rn(__fmul_rn(0.1f, bx.x), d0.z), d0.x);
            float yy = __fadd_rn(__fmul_rn(__fmul_rn(0.1f, by.x), d0.w), d0.y);
            float wx = __fmul_rn(expf(__fmul_rn(0.2f, bw.x)), d0.z);
            float wy = __fmul_rn(expf(__fmul_rn(0.2f, bh.x)), d0.w);
            float4 o;
            o.x = __fsub_rn(xx, __fmul_rn(0.5f, wx));
            o.y = __fsub_rn(yy, __fmul_rn(0.5f, wy));
            o.z = __fadd_rn(xx, __fmul_rn(0.5f, wx));
            o.w = __fadd_rn(yy, __fmul_rn(0.5f, wy));
            ltrb[(size_t)b * NBOX + n0] = o;
        }
        {
            float xx = __fadd_rn(__fmul_rn(__fmul_rn(0.1f, bx.y), d1.z), d1.x);
            float yy = __fadd_rn(__fmul_rn(__fmul_rn(0.1f, by.y), d1.w), d1.y);
            float wx = __fmul_rn(expf(__fmul_rn(0.2f, bw.y)), d1.z);
            float wy = __fmul_rn(expf(__fmul_rn(0.2f, bh.y)), d1.w);
            float4 o;
            o.x = __fsub_rn(xx, __fmul_rn(0.5f, wx));
            o.y = __fsub_rn(yy, __fmul_rn(0.5f, wy));
            o.z = __fadd_rn(xx, __fmul_rn(0.5f, wx));
            o.w = __fadd_rn(yy, __fmul_rn(0.5f, wy));
            ltrb[(size_t)b * NBOX + n0 + 1] = o;
        }

        // ---- pass 1: max (fmaxf is order-exact; 9 loads in flight/group)
        {
            const float* p0 = srow + n0;
#pragma unroll
            for (int c0 = 0; c0 < NCLS; c0 += 9) {      // 81 = 9*9 exact
                float2 g[9];
#pragma unroll
                for (int u = 0; u < 9; ++u)
                    g[u] = *(const float2*)(p0 + (size_t)(c0 + u) * NBOX);
#pragma unroll
                for (int u = 0; u < 9; ++u) {
                    m0 = fmaxf(m0, g[u].x);
                    m1 = fmaxf(m1, g[u].y);
                }
            }
        }

        // ---- pass 2: EXACT sequential sum c=0..80 (laundered base; groups
        // give 9-deep MLP while the two add chains stay in program order)
        {
            uintptr_t su = (uintptr_t)(srow + n0);
            asm volatile("" : "+v"(su));
            const float* p1 = (const float*)su;
            float ss0 = 0.f, ss1 = 0.f;
#pragma unroll
            for (int c0 = 0; c0 < NCLS; c0 += 9) {
                float2 g[9];
#pragma unroll
                for (int u = 0; u < 9; ++u)
                    g[u] = *(const float2*)(p1 + (size_t)(c0 + u) * NBOX);
#pragma unroll
                for (int u = 0; u < 9; ++u) {
                    ss0 = __fadd_rn(ss0, expf(__fsub_rn(g[u].x, m0)));
                    ss1 = __fadd_rn(ss1, expf(__fsub_rn(g[u].y, m1)));
                }
            }
            s0 = ss0; s1 = ss1;
        }
        // p > 0.05  =>  v > m + log(0.05*s); margin 1e-3 >> logf error;
        // survivors re-tested below with the exact reference expression.
        thr0 = __fsub_rn(__fadd_rn(m0, logf(__fmul_rn(0.05f, s0))), 1e-3f);
        thr1 = __fsub_rn(__fadd_rn(m1, logf(__fmul_rn(0.05f, s1))), 1e-3f);
    }

    // ---- pass 3: emit survivors (laundered re-read, L3-resident)
    if (valid) {
        uintptr_t su2 = (uintptr_t)(srow + n0);
        asm volatile("" : "+v"(su2));
        const float* p2 = (const float*)su2;

        auto emit = [&](float v, float m, float s, int c, unsigned n) {
            // exact test — identical expression to validated rounds
            float p = __fdiv_rn(expf(__fsub_rn(v, m)), s);
            if (p > SCORE_THR) {
                int e = atomicAdd(&lcnt, 1);
                if (e < LCAP) {
                    list[e] = ((unsigned long long)__float_as_uint(p) << 32) |
                              ((unsigned long long)(unsigned)(c - 1) << 24) |
                              (unsigned long long)n;
                } else {
                    // overflow fallback (never taken on this data)
                    int pos = atomicAdd(&gcnt[b * NFG + (c - 1)], 1);
                    if (pos < GCAP)
                        gcand[(size_t)(b * NFG + (c - 1)) * GCAP + pos] =
                            ((unsigned long long)__float_as_uint(p) << 32) |
                            (unsigned long long)(0xFFFFFFFFu - n);
                }
            }
        };

#pragma unroll
        for (int c0 = 1; c0 < NCLS; c0 += 16) {         // 1..80 = 5 groups of 16
            float2 g[16];
#pragma unroll
            for (int u = 0; u < 16; ++u) {
                int c = c0 + u;
                g[u] = (c < NCLS) ? *(const float2*)(p2 + (size_t)c * NBOX)
                                  : make_float2(-1e30f, -1e30f);
            }
#pragma unroll
            for (int u = 0; u < 16; ++u) {
                int c = c0 + u;
                if (g[u].x > thr0) emit(g[u].x, m0, s0, c, (unsigned)n0);
                if (g[u].y > thr1) emit(g[u].y, m1, s1, c, (unsigned)(n0 + 1));
            }
        }
    }
    __syncthreads();

    const int E = min(lcnt, LCAP);

    // ---- phase 4: per-class histogram (LDS atomics)
    for (int i = tid; i < E; i += 256) {
        int c = (int)((list[i] >> 24) & 0xFF);
        atomicAdd(&ccnt[c], 1);
    }
    __syncthreads();

    // ---- phase 5: one global atomic per (block, class) to reserve ranges
    if (tid < NFG && ccnt[tid] > 0)
        cbase[tid] = atomicAdd(&gcnt[b * NFG + tid], ccnt[tid]);
    __syncthreads();
    if (tid < NFG) ccnt[tid] = 0;   // reuse as cursor
    __syncthreads();

    // ---- phase 6: scatter entries to reserved slots
    for (int i = tid; i < E; i += 256) {
        unsigned long long e = list[i];
        int c = (int)((e >> 24) & 0xFF);
        unsigned nn = (unsigned)(e & 0xFFFFFF);
        int pos = cbase[c] + atomicAdd(&ccnt[c], 1);
        if (pos < GCAP) {
            unsigned pb = (unsigned)(e >> 32);
            gcand[(size_t)(b * NFG + c) * GCAP + pos] =
                ((unsigned long long)pb << 32) |
                (unsigned long long)(0xFFFFFFFFu - nn);
        }
    }
}

// ---------------------------------------------------------------- register bitonic sort (NR*64 items, NR/lane, no barriers)
// Compile-time network: j>=64 -> register-pair swap; j<64 -> shfl_xor.
// All register indices are compile-time (rule #20: no scratch).
template<int NR, int J, int K>
__device__ __forceinline__ void bstep(unsigned long long (&it)[NR], const int lane) {
    if constexpr (J >= 64) {
        constexpr int M = J >> 6;
#pragma unroll
        for (int r = 0; r < NR; ++r) {
            const int rp = r ^ M;
            if (rp > r) {
                const bool desc = (((unsigned)(r << 6) & (unsigned)K) == 0u);
                unsigned long long a = it[r], bb = it[rp];
                if (desc ? (a < bb) : (a > bb)) { it[r] = bb; it[rp] = a; }
            }
        }
    } else {
#pragma unroll
        for (int r = 0; r < NR; ++r) {
            unsigned long long a = it[r];
            unsigned long long bb = __shfl_xor(a, J, 64);
            const unsigned i = ((unsigned)(r << 6)) | (unsigned)lane;
            const bool desc = ((i & (unsigned)K) == 0u);
            const bool lower = ((lane & J) == 0);
            it[r] = ((desc == lower) ? (a >= bb) : (a <= bb)) ? a : bb;
        }
    }
}

template<int NR, int K, int J>
__device__ __forceinline__ void bstage(unsigned long long (&it)[NR], const int lane) {
    bstep<NR, J, K>(it, lane);
    if constexpr (J > 1) bstage<NR, K, (J >> 1)>(it, lane);
}

template<int NR>
__device__ __forceinline__ void bsort(unsigned long long (&it)[NR], const int lane,
                                      const unsigned kmax) {
    bstage<NR, 2, 1>(it, lane);
    if (kmax >= 4)   bstage<NR, 4, 2>(it, lane);
    if (kmax >= 8)   bstage<NR, 8, 4>(it, lane);
    if (kmax >= 16)  bstage<NR, 16, 8>(it, lane);
    if (kmax >= 32)  bstage<NR, 32, 16>(it, lane);
    if (kmax >= 64)  bstage<NR, 64, 32>(it, lane);
    if constexpr (NR >= 4) {
        if (kmax >= 128) bstage<NR, 128, 64>(it, lane);
        if (kmax >= 256) bstage<NR, 256, 128>(it, lane);
    }
    if constexpr (NR >= 8)  { if (kmax >= 512)  bstage<NR, 512, 256>(it, lane); }
    if constexpr (NR >= 16) { if (kmax >= 1024) bstage<NR, 1024, 512>(it, lane); }
}

// ---------------------------------------------------------------- K2: one wave per (image,class): reg-sort + fused greedy NMS
// ROUND-7/8 LESSON: barrier-latency bound -> one wave, zero barriers.
// ROUND-9/10 LESSON: grid-limited occupancy -> cut per-wave critical path
// (cl-sized sort network; prefetch-one-row-ahead greedy NMS).
__global__ __launch_bounds__(64) void k2_nms(
    const unsigned long long* __restrict__ gcand,  // [NTASK*GCAP]
    const int* __restrict__ gcnt,                  // [NTASK]
    const float4* __restrict__ ltrb,               // [B*N]
    float* __restrict__ cls_scores,                // [NTASK*200]
    int* __restrict__ cls_idx)                     // [NTASK*200] global ltrb index
{
    const int t = blockIdx.x;       // task = b*80 + (c-1)
    const int b = t / NFG;
    const int lane = threadIdx.x;   // 0..63

    __shared__ float4 sbox[TOPK];
    __shared__ float sarea[TOPK];

    const int cl = min(gcnt[t], SORTCAP);
    const unsigned long long* gc = gcand + (size_t)t * GCAP;

    unsigned kmax = 2;
    while (kmax < (unsigned)cl) kmax <<= 1;

    // sort descending into top4 (items 0..255 = r*64+lane, r<4)
    unsigned long long top4[4];
    if (cl <= 256) {
        unsigned long long it[4];
#pragma unroll
        for (int r = 0; r < 4; ++r) {
            const int i = (r << 6) + lane;
            it[r] = (i < cl) ? gc[i] : 0ULL;
        }
        bsort<4>(it, lane, kmax);
#pragma unroll
        for (int r = 0; r < 4; ++r) top4[r] = it[r];
    } else if (cl <= 512) {
        unsigned long long it[8];
#pragma unroll
        for (int r = 0; r < 8; ++r) {
            const int i = (r << 6) + lane;
            it[r] = (i < cl) ? gc[i] : 0ULL;
        }
        bsort<8>(it, lane, kmax);
#pragma unroll
        for (int r = 0; r < 4; ++r) top4[r] = it[r];
    } else {
        unsigned long long it[16];
#pragma unroll
        for (int r = 0; r < 16; ++r) {
            const int i = (r << 6) + lane;
            it[r] = (i < cl) ? gc[i] : 0ULL;
        }
        bsort<16>(it, lane, kmax);
#pragma unroll
        for (int r = 0; r < 4; ++r) top4[r] = it[r];
    }

    const int mk = min(cl, TOPK);

    // gather top-mk boxes; lane owns items/cols i = r*64+lane, r<4
    float4 myb[4];
    float mya[4], myp[4];
    int myn[4];
#pragma unroll
    for (int r = 0; r < 4; ++r) {
        const int i = (r << 6) + lane;
        myb[r] = make_float4(0.f, 0.f, 0.f, 0.f);
        mya[r] = 0.f; myp[r] = 0.f; myn[r] = 0;
        if (i < mk) {
            const unsigned long long key = top4[r];
            const unsigned n = 0xFFFFFFFFu - (unsigned)(key & 0xFFFFFFFFull);
            const float4 bx = ltrb[(size_t)b * NBOX + n];
            myb[r] = bx;
            mya[r] = __fmul_rn(__fsub_rn(bx.z, bx.x), __fsub_rn(bx.w, bx.y));
            myp[r] = __uint_as_float((unsigned)(key >> 32));
            myn[r] = b * NBOX + (int)n;
            sbox[i] = bx;
            sarea[i] = mya[r];
        }
    }
    __syncthreads();    // 1 wave: compiles to waitcnt + immediate barrier

    // fused greedy NMS: serial over sorted i; all lanes keep identical kw
    // (ballot result is uniform). Suppressed rows cost only the bit test.
    // Row i+1's box is PREFETCHED while row i is processed.
    // IoU replicates reference's unclamped deltas; identical FP expressions.
    auto maskBits = [](int r) -> unsigned long long {
        if (r <= 0) return 0ULL;
        if (r >= 64) return ~0ULL;
        return (1ULL << r) - 1ULL;
    };
    unsigned long long kw0 = maskBits(mk);
    unsigned long long kw1 = maskBits(mk - 64);
    unsigned long long kw2 = maskBits(mk - 128);
    unsigned long long kw3 = maskBits(mk - 192);

    float4 nb = sbox[0];
    float na = sarea[0];

#define NMS_QUAD(KWQ, Q)                                                           \
    {                                                                              \
        const int i0 = (Q) << 6;                                                   \
        const int i1 = min(mk, i0 + 64);                                           \
        for (int i = i0; i < i1; ++i) {                                            \
            const float4 bi = nb;                                                  \
            const float ai = na;                                                   \
            const int ip = min(i + 1, TOPK - 1);                                   \
            nb = sbox[ip];                                                         \
            na = sarea[ip];                                                        \
            if ((KWQ >> (i - i0)) & 1ULL) {                                        \
                _Pragma("unroll")                                                  \
                for (int q2 = 0; q2 < 4; ++q2) {                                   \
                    const int j = (q2 << 6) + lane;                                \
                    const float4 bj = myb[q2];                                     \
                    const float ltx = fmaxf(bi.x, bj.x), lty = fmaxf(bi.y, bj.y);  \
                    const float rbx = fminf(bi.z, bj.z), rby = fminf(bi.w, bj.w);  \
                    const float dx = __fsub_rn(rbx, ltx), dy = __fsub_rn(rby, lty);\
                    const float inter = __fmul_rn(dx, dy);                         \
                    const float uni = __fsub_rn(__fadd_rn(ai, mya[q2]), inter);    \
                    const float iou = __fdiv_rn(inter, uni);                       \
                    const unsigned long long sup =                                 \
                        __ballot((iou >= CRITERIA) && (j > i));                    \
                    if (q2 == 0) kw0 &= ~sup;                                      \
                    else if (q2 == 1) kw1 &= ~sup;                                 \
                    else if (q2 == 2) kw2 &= ~sup;                                 \
                    else kw3 &= ~sup;                                              \
                }                                                                  \
            }                                                                      \
        }                                                                          \
    }
    NMS_QUAD(kw0, 0)
    NMS_QUAD(kw1, 1)
    NMS_QUAD(kw2, 2)
    NMS_QUAD(kw3, 3)
#undef NMS_QUAD

    // write per-class results (coalesced per r-group)
#pragma unroll
    for (int r = 0; r < 4; ++r) {
        const int i = (r << 6) + lane;
        if (i < TOPK) {
            const unsigned long long kq = (r == 0) ? kw0 : (r == 1) ? kw1
                                         : (r == 2) ? kw2 : kw3;
            const bool keep = (i < mk) && ((kq >> lane) & 1ULL);
            cls_scores[(size_t)t * TOPK + i] = keep ? myp[r] : NEG_INF;
            if (i < mk) cls_idx[(size_t)t * TOPK + i] = myn[r];
        }
    }
}

// ---------------------------------------------------------------- K3: per-image global top-200
__device__ __forceinline__ int blockReduceSum(int x, int* red, int tid) {
    __syncthreads();
    red[tid] = x;
    __syncthreads();
    for (int off = 128; off > 0; off >>= 1) {
        if (tid < off) red[tid] += red[tid + off];
        __syncthreads();
    }
    return red[0];
}

__global__ __launch_bounds__(256) void k3_topk(
    const float* __restrict__ cls_scores,   // [B*80*200]
    const int* __restrict__ cls_idx,        // [B*80*200]
    const float4* __restrict__ ltrb,        // [B*N]
    float* __restrict__ out)
{
    const int b = blockIdx.x;
    const int tid = threadIdx.x;
    const int NFLAT = NFG * TOPK;           // 16000
    const int PER = 63;

    __shared__ unsigned long long sel[512];
    __shared__ int scnt;
    __shared__ int red[256];

    const float* S = cls_scores + (size_t)b * NFLAT;
    float v[PER];
#pragma unroll
    for (int i = 0; i < PER; ++i) {
        int j = i * 256 + tid;
        v[i] = (j < NFLAT) ? S[j] : NEG_INF;
    }

    int lc = 0;
#pragma unroll
    for (int i = 0; i < PER; ++i) lc += (v[i] > -1e29f) ? 1 : 0;
    int validCount = blockReduceSum(lc, red, tid);

    unsigned thrBits = 0;
    if (validCount > TOPK) {
        unsigned lo = 0, hi = 0x7F800000u;
        while (lo < hi) {
            unsigned mid = (lo + hi) >> 1;
            float mf = __uint_as_float(mid);
            int c2 = 0;
#pragma unroll
            for (int i = 0; i < PER; ++i) c2 += (v[i] > mf) ? 1 : 0;
            int tot = blockReduceSum(c2, red, tid);
            if (tot < TOPK) hi = mid; else lo = mid + 1;
        }
        thrBits = lo;
    }

    __syncthreads();
    if (tid == 0) scnt = 0;
    for (int i = tid; i < 512; i += 256) sel[i] = 0ULL;
    __syncthreads();

    const bool useGE = (validCount > TOPK);
    const float thrF = __uint_as_float(thrBits);
#pragma unroll
    for (int i = 0; i < PER; ++i) {
        int j = i * 256 + tid;
        bool take = useGE ? (v[i] >= thrF) : (v[i] > -1e29f);
        if (j < NFLAT && take) {
            int pos = atomicAdd(&scnt, 1);
            if (pos < 512) {
                sel[pos] = ((unsigned long long)__float_as_uint(v[i]) << 32) |
                           (unsigned long long)(0xFFFFFFFFu - (unsigned)j);
            }
        }
    }
    __syncthreads();
    int total = min(min(scnt, 512), TOPK);

    for (unsigned k = 2; k <= 512; k <<= 1) {
        for (unsigned j = k >> 1; j > 0; j >>= 1) {
            for (unsigned i = tid; i < 512; i += 256) {
                unsigned ixj = i ^ j;
                if (ixj > i) {
                    unsigned long long a = sel[i], bb2 = sel[ixj];
                    bool desc = ((i & k) == 0);
                    if (desc ? (a < bb2) : (a > bb2)) { sel[i] = bb2; sel[ixj] = a; }
                }
            }
            __syncthreads();
        }
    }

    if (tid < TOPK) {
        size_t ob = (size_t)b * TOPK + tid;
        float4 bx = make_float4(0.f, 0.f, 0.f, 0.f);
        float lab = 0.f, sc2 = 0.f;
        if (tid < total) {
            unsigned long long key = sel[tid];
            unsigned j = 0xFFFFFFFFu - (unsigned)(key & 0xFFFFFFFFull);
            sc2 = __uint_as_float((unsigned)(key >> 32));
            unsigned cls = j / TOPK;
            int gi = cls_idx[(size_t)b * NFLAT + j];
            bx = ltrb[gi];
            lab = (float)(cls + 1);
        }
        reinterpret_cast<float4*>(out)[ob] = bx;
        out[(size_t)BATCH * TOPK * 4 + ob] = lab;
        out[(size_t)BATCH * TOPK * 4 + (size_t)BATCH * TOPK + ob] = sc2;
    }
}

// ---------------------------------------------------------------- launch
extern "C" void kernel_launch(void* const* d_in, const int* in_sizes, int n_in,
                              void* d_out, int out_size, void* d_ws, size_t ws_size,
                              hipStream_t stream) {
    (void)in_sizes; (void)n_in; (void)out_size; (void)ws_size;
    const float* bboxes = (const float*)d_in[0];   // [32,4,15130]
    const float* scores = (const float*)d_in[1];   // [32,81,15130]
    const float* dboxes = (const float*)d_in[2];   // [1,15130,4]
    float* out = (float*)d_out;

    char* ws = (char*)d_ws;
    size_t off = 0;
    float4* ltrb = (float4*)(ws + off);      off += (size_t)BATCH * NBOX * 16;    //  7,746,560
    unsigned long long* gcand = (unsigned long long*)(ws + off);
                                             off += (size_t)NTASK * GCAP * 8;     // 20,971,520
    float* cls_scores = (float*)(ws + off);  off += (size_t)NTASK * TOPK * 4;     //  2,048,000
    int*   cls_idx    = (int*)(ws + off);    off += (size_t)NTASK * TOPK * 4;     //  2,048,000
    int*   gcnt       = (int*)(ws + off);    off += (size_t)NTASK * 4;            //     10,240

    hipMemsetAsync(gcnt, 0, NTASK * sizeof(int), stream);

    k1_fused<<<BATCH * NCHUNK2, 256, 0, stream>>>(bboxes, scores, dboxes, ltrb, gcand, gcnt);
    k2_nms<<<NTASK, 64, 0, stream>>>(gcand, gcnt, ltrb, cls_scores, cls_idx);
    k3_topk<<<BATCH, 256, 0, stream>>>(cls_scores, cls_idx, ltrb, out);
}

// Round 13
// 269.747 us; speedup vs baseline: 1.4426x; 1.4426x over previous
//
#include <hip/hip_runtime.h>
#include <cstdint>
#include <cstddef>

#define BATCH 32
#define NCLS 81
#define NFG 80
#define NBOX 15130
#define TW 128            // boxes per k1 block (= threads)
#define NCHUNK3 119       // ceil(15130/128)
#define TOPK 200
#define NTASK (BATCH * NFG)
#define NEG_INF -1e30f
#define GCAP 1024         // per-task candidate capacity (measured mean ~434)
#define SORTCAP 1024
#define LCAP 768          // per-block survivor list; E~294 expected, fallback below
#define SCORE_THR 0.05f
#define CRITERIA 0.45f

// ---------------------------------------------------------------- K1: decode + softmax + compacted candidate emission
// ROUND-10/11/12 LESSON: an 81-value per-thread working set cannot be made
// register-resident at HIP level — the allocator either re-loads inside the
// reduction chain (VGPR=56, latency-bound, 103 us) or doubles liveness
// (VGPR=184, occupancy 11%, 328 us). Fix: put the working set in LDS via
// global_load_lds (zero VGPR cost per load, up to 63 outstanding per wave).
// The [81][128] tile is staged ONCE; max/sum/emit all read LDS. Scores
// leave HBM exactly once. Sum order stays EXACT sequential c=0..80.
// ROUND-3 LESSON: no per-element global atomics on few hot addresses.
// ROUND-4/5/6 LESSON: k2 must read compacted lists, not re-stream scores.
__global__ __launch_bounds__(128) void k1_fused(
    const float* __restrict__ bboxes,   // [B,4,N]
    const float* __restrict__ scores,   // [B,C,N]
    const float* __restrict__ dboxes,   // [N,4]
    float4* __restrict__ ltrb,          // [B*N]
    unsigned long long* __restrict__ gcand,  // [NTASK*GCAP]
    int* __restrict__ gcnt)             // [NTASK] (zeroed before launch)
{
    const int blk = blockIdx.x;
    const int b = blk / NCHUNK3;
    const int chunk = blk - b * NCHUNK3;
    const int tid = threadIdx.x;        // 0..127
    const int lane = tid & 63;
    const int w = tid >> 6;             // wave 0..1
    const int nbase = chunk * TW;
    const int n = nbase + tid;
    const bool valid = (n < NBOX);

    __shared__ float tile[NCLS][TW];            // 41,472 B
    __shared__ unsigned long long list[LCAP];   // 6,144 B: (p<<32)|(cfg<<24)|n
    __shared__ int lcnt;
    __shared__ int ccnt[NFG];
    __shared__ int cbase[NFG];

    if (tid == 0) lcnt = 0;
    if (tid < NFG) ccnt[tid] = 0;

    // ---- decode first (short; its loads complete before staging floods vmcnt)
    if (valid) {
        const float* bb = bboxes + (size_t)b * 4 * NBOX + n;
        float bx = bb[0];
        float by = bb[NBOX];
        float bw = bb[2 * (size_t)NBOX];
        float bh = bb[3 * (size_t)NBOX];
        float4 d = reinterpret_cast<const float4*>(dboxes)[n];  // cx, cy, w, h
        float xx = __fadd_rn(__fmul_rn(__fmul_rn(0.1f, bx), d.z), d.x);
        float yy = __fadd_rn(__fmul_rn(__fmul_rn(0.1f, by), d.w), d.y);
        float wx = __fmul_rn(expf(__fmul_rn(0.2f, bw)), d.z);
        float wy = __fmul_rn(expf(__fmul_rn(0.2f, bh)), d.w);
        float4 o;
        o.x = __fsub_rn(xx, __fmul_rn(0.5f, wx));
        o.y = __fsub_rn(yy, __fmul_rn(0.5f, wy));
        o.z = __fadd_rn(xx, __fmul_rn(0.5f, wx));
        o.w = __fadd_rn(yy, __fmul_rn(0.5f, wy));
        ltrb[(size_t)b * NBOX + n] = o;
    }

    // ---- stage all 81 rows into LDS. Per rule #21: LDS dest is wave-uniform
    // base + lane*4 (columns w*64+lane); global src is per-lane (coalesced
    // 256 B per instruction). Exec mask guards tail-chunk OOB lanes — masked
    // lanes neither read global nor write LDS.
    {
        const float* gp = scores + (size_t)b * NCLS * NBOX + nbase + (w << 6) + lane;
        if (nbase + (w << 6) + lane < NBOX) {
#pragma unroll
            for (int c = 0; c < NCLS; ++c) {
                __builtin_amdgcn_global_load_lds(
                    (const void*)(gp + (size_t)c * NBOX),
                    (void*)&tile[c][w << 6], 4, 0, 0);
            }
        }
    }
    __syncthreads();    // drains vmcnt(0): tile fully resident

    // ---- passes over LDS (column tid): max, EXACT-order sum, threshold
    float m = -INFINITY, ssum = 1.f, thrv = 1e30f;
    if (valid) {
        float mm = tile[0][tid];
#pragma unroll
        for (int c = 1; c < NCLS; ++c) mm = fmaxf(mm, tile[c][tid]);
        m = mm;
        float ss = 0.0f;
#pragma unroll
        for (int c = 0; c < NCLS; ++c)
            ss = __fadd_rn(ss, expf(__fsub_rn(tile[c][tid], m)));
        ssum = ss;
        // p > 0.05  =>  v > m + log(0.05*s); margin 1e-3 >> logf error;
        // survivors re-tested below with the exact reference expression.
        thrv = __fsub_rn(__fadd_rn(m, logf(__fmul_rn(0.05f, ssum))), 1e-3f);
    }

    // ---- emit survivors from LDS (exact validated expression decides)
    if (valid) {
#pragma unroll
        for (int c = 1; c < NCLS; ++c) {
            float v = tile[c][tid];
            if (v > thrv) {
                float p = __fdiv_rn(expf(__fsub_rn(v, m)), ssum);
                if (p > SCORE_THR) {
                    int e = atomicAdd(&lcnt, 1);
                    if (e < LCAP) {
                        list[e] = ((unsigned long long)__float_as_uint(p) << 32) |
                                  ((unsigned long long)(unsigned)(c - 1) << 24) |
                                  (unsigned long long)(unsigned)n;
                    } else {
                        // overflow fallback (never taken: needs 6+ survivors/box
                        // vs 2.3 measured) — direct per-entry global reservation
                        int pos = atomicAdd(&gcnt[b * NFG + (c - 1)], 1);
                        if (pos < GCAP)
                            gcand[(size_t)(b * NFG + (c - 1)) * GCAP + pos] =
                                ((unsigned long long)__float_as_uint(p) << 32) |
                                (unsigned long long)(0xFFFFFFFFu - (unsigned)n);
                    }
                }
            }
        }
    }
    __syncthreads();

    const int E = min(lcnt, LCAP);

    // ---- per-class histogram (LDS atomics)
    for (int i = tid; i < E; i += TW) {
        int c = (int)((list[i] >> 24) & 0xFF);
        atomicAdd(&ccnt[c], 1);
    }
    __syncthreads();

    // ---- one global atomic per (block, class) to reserve ranges
    if (tid < NFG && ccnt[tid] > 0)
        cbase[tid] = atomicAdd(&gcnt[b * NFG + tid], ccnt[tid]);
    __syncthreads();
    if (tid < NFG) ccnt[tid] = 0;   // reuse as cursor
    __syncthreads();

    // ---- scatter entries to reserved slots
    for (int i = tid; i < E; i += TW) {
        unsigned long long e = list[i];
        int c = (int)((e >> 24) & 0xFF);
        unsigned nn = (unsigned)(e & 0xFFFFFF);
        int pos = cbase[c] + atomicAdd(&ccnt[c], 1);
        if (pos < GCAP) {
            unsigned pb = (unsigned)(e >> 32);
            gcand[(size_t)(b * NFG + c) * GCAP + pos] =
                ((unsigned long long)pb << 32) |
                (unsigned long long)(0xFFFFFFFFu - nn);
        }
    }
}

// ---------------------------------------------------------------- register bitonic sort (NR*64 items, NR/lane, no barriers)
// Compile-time network: j>=64 -> register-pair swap; j<64 -> shfl_xor.
// All register indices are compile-time (rule #20: no scratch).
template<int NR, int J, int K>
__device__ __forceinline__ void bstep(unsigned long long (&it)[NR], const int lane) {
    if constexpr (J >= 64) {
        constexpr int M = J >> 6;
#pragma unroll
        for (int r = 0; r < NR; ++r) {
            const int rp = r ^ M;
            if (rp > r) {
                const bool desc = (((unsigned)(r << 6) & (unsigned)K) == 0u);
                unsigned long long a = it[r], bb = it[rp];
                if (desc ? (a < bb) : (a > bb)) { it[r] = bb; it[rp] = a; }
            }
        }
    } else {
#pragma unroll
        for (int r = 0; r < NR; ++r) {
            unsigned long long a = it[r];
            unsigned long long bb = __shfl_xor(a, J, 64);
            const unsigned i = ((unsigned)(r << 6)) | (unsigned)lane;
            const bool desc = ((i & (unsigned)K) == 0u);
            const bool lower = ((lane & J) == 0);
            it[r] = ((desc == lower) ? (a >= bb) : (a <= bb)) ? a : bb;
        }
    }
}

template<int NR, int K, int J>
__device__ __forceinline__ void bstage(unsigned long long (&it)[NR], const int lane) {
    bstep<NR, J, K>(it, lane);
    if constexpr (J > 1) bstage<NR, K, (J >> 1)>(it, lane);
}

template<int NR>
__device__ __forceinline__ void bsort(unsigned long long (&it)[NR], const int lane,
                                      const unsigned kmax) {
    bstage<NR, 2, 1>(it, lane);
    if (kmax >= 4)   bstage<NR, 4, 2>(it, lane);
    if (kmax >= 8)   bstage<NR, 8, 4>(it, lane);
    if (kmax >= 16)  bstage<NR, 16, 8>(it, lane);
    if (kmax >= 32)  bstage<NR, 32, 16>(it, lane);
    if (kmax >= 64)  bstage<NR, 64, 32>(it, lane);
    if constexpr (NR >= 4) {
        if (kmax >= 128) bstage<NR, 128, 64>(it, lane);
        if (kmax >= 256) bstage<NR, 256, 128>(it, lane);
    }
    if constexpr (NR >= 8)  { if (kmax >= 512)  bstage<NR, 512, 256>(it, lane); }
    if constexpr (NR >= 16) { if (kmax >= 1024) bstage<NR, 1024, 512>(it, lane); }
}

// ---------------------------------------------------------------- K2: one wave per (image,class): reg-sort + fused greedy NMS
// ROUND-7/8 LESSON: barrier-latency bound -> one wave, zero barriers.
// ROUND-9/10 LESSON: grid-limited occupancy -> cut per-wave critical path
// (cl-sized sort network; prefetch-one-row-ahead greedy NMS).
__global__ __launch_bounds__(64) void k2_nms(
    const unsigned long long* __restrict__ gcand,  // [NTASK*GCAP]
    const int* __restrict__ gcnt,                  // [NTASK]
    const float4* __restrict__ ltrb,               // [B*N]
    float* __restrict__ cls_scores,                // [NTASK*200]
    int* __restrict__ cls_idx)                     // [NTASK*200] global ltrb index
{
    const int t = blockIdx.x;       // task = b*80 + (c-1)
    const int b = t / NFG;
    const int lane = threadIdx.x;   // 0..63

    __shared__ float4 sbox[TOPK];
    __shared__ float sarea[TOPK];

    const int cl = min(gcnt[t], SORTCAP);
    const unsigned long long* gc = gcand + (size_t)t * GCAP;

    unsigned kmax = 2;
    while (kmax < (unsigned)cl) kmax <<= 1;

    // sort descending into top4 (items 0..255 = r*64+lane, r<4)
    unsigned long long top4[4];
    if (cl <= 256) {
        unsigned long long it[4];
#pragma unroll
        for (int r = 0; r < 4; ++r) {
            const int i = (r << 6) + lane;
            it[r] = (i < cl) ? gc[i] : 0ULL;
        }
        bsort<4>(it, lane, kmax);
#pragma unroll
        for (int r = 0; r < 4; ++r) top4[r] = it[r];
    } else if (cl <= 512) {
        unsigned long long it[8];
#pragma unroll
        for (int r = 0; r < 8; ++r) {
            const int i = (r << 6) + lane;
            it[r] = (i < cl) ? gc[i] : 0ULL;
        }
        bsort<8>(it, lane, kmax);
#pragma unroll
        for (int r = 0; r < 4; ++r) top4[r] = it[r];
    } else {
        unsigned long long it[16];
#pragma unroll
        for (int r = 0; r < 16; ++r) {
            const int i = (r << 6) + lane;
            it[r] = (i < cl) ? gc[i] : 0ULL;
        }
        bsort<16>(it, lane, kmax);
#pragma unroll
        for (int r = 0; r < 4; ++r) top4[r] = it[r];
    }

    const int mk = min(cl, TOPK);

    // gather top-mk boxes; lane owns items/cols i = r*64+lane, r<4
    float4 myb[4];
    float mya[4], myp[4];
    int myn[4];
#pragma unroll
    for (int r = 0; r < 4; ++r) {
        const int i = (r << 6) + lane;
        myb[r] = make_float4(0.f, 0.f, 0.f, 0.f);
        mya[r] = 0.f; myp[r] = 0.f; myn[r] = 0;
        if (i < mk) {
            const unsigned long long key = top4[r];
            const unsigned n = 0xFFFFFFFFu - (unsigned)(key & 0xFFFFFFFFull);
            const float4 bx = ltrb[(size_t)b * NBOX + n];
            myb[r] = bx;
            mya[r] = __fmul_rn(__fsub_rn(bx.z, bx.x), __fsub_rn(bx.w, bx.y));
            myp[r] = __uint_as_float((unsigned)(key >> 32));
            myn[r] = b * NBOX + (int)n;
            sbox[i] = bx;
            sarea[i] = mya[r];
        }
    }
    __syncthreads();    // 1 wave: compiles to waitcnt + immediate barrier

    // fused greedy NMS: serial over sorted i; all lanes keep identical kw
    // (ballot result is uniform). Suppressed rows cost only the bit test.
    // Row i+1's box is PREFETCHED while row i is processed.
    // IoU replicates reference's unclamped deltas; identical FP expressions.
    auto maskBits = [](int r) -> unsigned long long {
        if (r <= 0) return 0ULL;
        if (r >= 64) return ~0ULL;
        return (1ULL << r) - 1ULL;
    };
    unsigned long long kw0 = maskBits(mk);
    unsigned long long kw1 = maskBits(mk - 64);
    unsigned long long kw2 = maskBits(mk - 128);
    unsigned long long kw3 = maskBits(mk - 192);

    float4 nb = sbox[0];
    float na = sarea[0];

#define NMS_QUAD(KWQ, Q)                                                           \
    {                                                                              \
        const int i0 = (Q) << 6;                                                   \
        const int i1 = min(mk, i0 + 64);                                           \
        for (int i = i0; i < i1; ++i) {                                            \
            const float4 bi = nb;                                                  \
            const float ai = na;                                                   \
            const int ip = min(i + 1, TOPK - 1);                                   \
            nb = sbox[ip];                                                         \
            na = sarea[ip];                                                        \
            if ((KWQ >> (i - i0)) & 1ULL) {                                        \
                _Pragma("unroll")                                                  \
                for (int q2 = 0; q2 < 4; ++q2) {                                   \
                    const int j = (q2 << 6) + lane;                                \
                    const float4 bj = myb[q2];                                     \
                    const float ltx = fmaxf(bi.x, bj.x), lty = fmaxf(bi.y, bj.y);  \
                    const float rbx = fminf(bi.z, bj.z), rby = fminf(bi.w, bj.w);  \
                    const float dx = __fsub_rn(rbx, ltx), dy = __fsub_rn(rby, lty);\
                    const float inter = __fmul_rn(dx, dy);                         \
                    const float uni = __fsub_rn(__fadd_rn(ai, mya[q2]), inter);    \
                    const float iou = __fdiv_rn(inter, uni);                       \
                    const unsigned long long sup =                                 \
                        __ballot((iou >= CRITERIA) && (j > i));                    \
                    if (q2 == 0) kw0 &= ~sup;                                      \
                    else if (q2 == 1) kw1 &= ~sup;                                 \
                    else if (q2 == 2) kw2 &= ~sup;                                 \
                    else kw3 &= ~sup;                                              \
                }                                                                  \
            }                                                                      \
        }                                                                          \
    }
    NMS_QUAD(kw0, 0)
    NMS_QUAD(kw1, 1)
    NMS_QUAD(kw2, 2)
    NMS_QUAD(kw3, 3)
#undef NMS_QUAD

    // write per-class results (coalesced per r-group)
#pragma unroll
    for (int r = 0; r < 4; ++r) {
        const int i = (r << 6) + lane;
        if (i < TOPK) {
            const unsigned long long kq = (r == 0) ? kw0 : (r == 1) ? kw1
                                         : (r == 2) ? kw2 : kw3;
            const bool keep = (i < mk) && ((kq >> lane) & 1ULL);
            cls_scores[(size_t)t * TOPK + i] = keep ? myp[r] : NEG_INF;
            if (i < mk) cls_idx[(size_t)t * TOPK + i] = myn[r];
        }
    }
}

// ---------------------------------------------------------------- K3: per-image global top-200
__device__ __forceinline__ int blockReduceSum(int x, int* red, int tid) {
    __syncthreads();
    red[tid] = x;
    __syncthreads();
    for (int off = 128; off > 0; off >>= 1) {
        if (tid < off) red[tid] += red[tid + off];
        __syncthreads();
    }
    return red[0];
}

__global__ __launch_bounds__(256) void k3_topk(
    const float* __restrict__ cls_scores,   // [B*80*200]
    const int* __restrict__ cls_idx,        // [B*80*200]
    const float4* __restrict__ ltrb,        // [B*N]
    float* __restrict__ out)
{
    const int b = blockIdx.x;
    const int tid = threadIdx.x;
    const int NFLAT = NFG * TOPK;           // 16000
    const int PER = 63;

    __shared__ unsigned long long sel[512];
    __shared__ int scnt;
    __shared__ int red[256];

    const float* S = cls_scores + (size_t)b * NFLAT;
    float v[PER];
#pragma unroll
    for (int i = 0; i < PER; ++i) {
        int j = i * 256 + tid;
        v[i] = (j < NFLAT) ? S[j] : NEG_INF;
    }

    int lc = 0;
#pragma unroll
    for (int i = 0; i < PER; ++i) lc += (v[i] > -1e29f) ? 1 : 0;
    int validCount = blockReduceSum(lc, red, tid);

    unsigned thrBits = 0;
    if (validCount > TOPK) {
        unsigned lo = 0, hi = 0x7F800000u;
        while (lo < hi) {
            unsigned mid = (lo + hi) >> 1;
            float mf = __uint_as_float(mid);
            int c2 = 0;
#pragma unroll
            for (int i = 0; i < PER; ++i) c2 += (v[i] > mf) ? 1 : 0;
            int tot = blockReduceSum(c2, red, tid);
            if (tot < TOPK) hi = mid; else lo = mid + 1;
        }
        thrBits = lo;
    }

    __syncthreads();
    if (tid == 0) scnt = 0;
    for (int i = tid; i < 512; i += 256) sel[i] = 0ULL;
    __syncthreads();

    const bool useGE = (validCount > TOPK);
    const float thrF = __uint_as_float(thrBits);
#pragma unroll
    for (int i = 0; i < PER; ++i) {
        int j = i * 256 + tid;
        bool take = useGE ? (v[i] >= thrF) : (v[i] > -1e29f);
        if (j < NFLAT && take) {
            int pos = atomicAdd(&scnt, 1);
            if (pos < 512) {
                sel[pos] = ((unsigned long long)__float_as_uint(v[i]) << 32) |
                           (unsigned long long)(0xFFFFFFFFu - (unsigned)j);
            }
        }
    }
    __syncthreads();
    int total = min(min(scnt, 512), TOPK);

    for (unsigned k = 2; k <= 512; k <<= 1) {
        for (unsigned j = k >> 1; j > 0; j >>= 1) {
            for (unsigned i = tid; i < 512; i += 256) {
                unsigned ixj = i ^ j;
                if (ixj > i) {
                    unsigned long long a = sel[i], bb2 = sel[ixj];
                    bool desc = ((i & k) == 0);
                    if (desc ? (a < bb2) : (a > bb2)) { sel[i] = bb2; sel[ixj] = a; }
                }
            }
            __syncthreads();
        }
    }

    if (tid < TOPK) {
        size_t ob = (size_t)b * TOPK + tid;
        float4 bx = make_float4(0.f, 0.f, 0.f, 0.f);
        float lab = 0.f, sc2 = 0.f;
        if (tid < total) {
            unsigned long long key = sel[tid];
            unsigned j = 0xFFFFFFFFu - (unsigned)(key & 0xFFFFFFFFull);
            sc2 = __uint_as_float((unsigned)(key >> 32));
            unsigned cls = j / TOPK;
            int gi = cls_idx[(size_t)b * NFLAT + j];
            bx = ltrb[gi];
            lab = (float)(cls + 1);
        }
        reinterpret_cast<float4*>(out)[ob] = bx;
        out[(size_t)BATCH * TOPK * 4 + ob] = lab;
        out[(size_t)BATCH * TOPK * 4 + (size_t)BATCH * TOPK + ob] = sc2;
    }
}

// ---------------------------------------------------------------- launch
extern "C" void kernel_launch(void* const* d_in, const int* in_sizes, int n_in,
                              void* d_out, int out_size, void* d_ws, size_t ws_size,
                              hipStream_t stream) {
    (void)in_sizes; (void)n_in; (void)out_size; (void)ws_size;
    const float* bboxes = (const float*)d_in[0];   // [32,4,15130]
    const float* scores = (const float*)d_in[1];   // [32,81,15130]
    const float* dboxes = (const float*)d_in[2];   // [1,15130,4]
    float* out = (float*)d_out;

    char* ws = (char*)d_ws;
    size_t off = 0;
    float4* ltrb = (float4*)(ws + off);      off += (size_t)BATCH * NBOX * 16;    //  7,746,560
    unsigned long long* gcand = (unsigned long long*)(ws + off);
                                             off += (size_t)NTASK * GCAP * 8;     // 20,971,520
    float* cls_scores = (float*)(ws + off);  off += (size_t)NTASK * TOPK * 4;     //  2,048,000
    int*   cls_idx    = (int*)(ws + off);    off += (size_t)NTASK * TOPK * 4;     //  2,048,000
    int*   gcnt       = (int*)(ws + off);    off += (size_t)NTASK * 4;            //     10,240

    hipMemsetAsync(gcnt, 0, NTASK * sizeof(int), stream);

    k1_fused<<<BATCH * NCHUNK3, TW, 0, stream>>>(bboxes, scores, dboxes, ltrb, gcand, gcnt);
    k2_nms<<<NTASK, 64, 0, stream>>>(gcand, gcnt, ltrb, cls_scores, cls_idx);
    k3_topk<<<BATCH, 256, 0, stream>>>(cls_scores, cls_idx, ltrb, out);
}

// Round 14
// 231.819 us; speedup vs baseline: 1.6786x; 1.1636x over previous
//
#include <hip/hip_runtime.h>
#include <cstdint>
#include <cstddef>

#define BATCH 32
#define NCLS 81
#define NFG 80
#define NBOX 15130
#define NCHUNK 60         // ceil(15130/256)
#define TOPK 200
#define NTASK (BATCH * NFG)
#define NEG_INF -1e30f
#define GCAP 1024         // per-task candidate capacity (measured mean ~434)
#define SORTCAP 1024
#define LCAP 1920         // per-chunk survivor list; measured E~590, fallback below
#define SCORE_THR 0.05f
#define CRITERIA 0.45f

// ---------------------------------------------------------------- K1: decode + softmax + compacted candidate emission
// ROUND-10..13 SYNTHESIS: the 81-value softmax working set cannot live in
// registers (whole-array -> compiler reloads at VGPR=56 or spills; 2-box ->
// VGPR=184; LDS tile -> occupancy 16% at 830 GB/s). This version: 1 box/
// thread, 16-wide load groups, 2-stage pipeline where group g+1's pointer
// is ASM-LAUNDERED WITH A DATA DEPENDENCE on the running max/sum through
// group g-1 — the scheduler cannot hoist loads beyond pipeline depth 2,
// capping liveness at ~48 floats while keeping 16-32 loads in flight.
// Sum order stays EXACT sequential c=0..80 (groups ascending, tail c=80
// last) — bit-exact p has held absmax 0.0 for 13 rounds.
// ROUND-3 LESSON: no per-element global atomics on few hot addresses.
// ROUND-4/5/6 LESSON: k2 must read compacted lists, not re-stream scores.
__global__ __launch_bounds__(256) void k1_fused(
    const float* __restrict__ bboxes,   // [B,4,N]
    const float* __restrict__ scores,   // [B,C,N]
    const float* __restrict__ dboxes,   // [N,4]
    float4* __restrict__ ltrb,          // [B*N]
    unsigned long long* __restrict__ gcand,  // [NTASK*GCAP]
    int* __restrict__ gcnt)             // [NTASK] (zeroed before launch)
{
    const int blk = blockIdx.x;
    const int b = blk / NCHUNK;
    const int chunk = blk - b * NCHUNK;
    const int tid = threadIdx.x;
    const int n = chunk * 256 + tid;
    const bool valid = (n < NBOX);

    __shared__ unsigned long long list[LCAP];   // (p_bits<<32)|(cfg<<24)|n
    __shared__ int lcnt;
    __shared__ int ccnt[NFG];
    __shared__ int cbase[NFG];

    if (tid == 0) lcnt = 0;
    if (tid < NFG) ccnt[tid] = 0;
    __syncthreads();

    float m = 0.f, ssum = 1.f, thrv = 1e30f;
    const float* scp = scores;

    if (valid) {
        // ---- decode (bit-exact expressions, validated rounds 1-13)
        const float* bb = bboxes + (size_t)b * 4 * NBOX + n;
        float bx = bb[0];
        float by = bb[NBOX];
        float bw = bb[2 * (size_t)NBOX];
        float bh = bb[3 * (size_t)NBOX];
        float4 d = reinterpret_cast<const float4*>(dboxes)[n];  // cx, cy, w, h
        float xx = __fadd_rn(__fmul_rn(__fmul_rn(0.1f, bx), d.z), d.x);
        float yy = __fadd_rn(__fmul_rn(__fmul_rn(0.1f, by), d.w), d.y);
        float wx = __fmul_rn(expf(__fmul_rn(0.2f, bw)), d.z);
        float wy = __fmul_rn(expf(__fmul_rn(0.2f, bh)), d.w);
        float4 o;
        o.x = __fsub_rn(xx, __fmul_rn(0.5f, wx));
        o.y = __fsub_rn(yy, __fmul_rn(0.5f, wy));
        o.z = __fadd_rn(xx, __fmul_rn(0.5f, wx));
        o.w = __fadd_rn(yy, __fmul_rn(0.5f, wy));
        ltrb[(size_t)b * NBOX + n] = o;

        scp = scores + (size_t)b * NCLS * NBOX + n;

        // ---- pass 1: max over c=0..80 (fmaxf order-exact). 2-stage pipeline:
        // group g+1 loads are dep-laundered on mm (through g-1) -> cannot be
        // hoisted past pipeline depth 2; 16 loads in flight while consuming.
        {
            float cur[16], nxt[16];
#pragma unroll
            for (int u = 0; u < 16; ++u) cur[u] = scp[(size_t)u * NBOX];
            float mm = -INFINITY;
            for (int g = 0; g < 5; ++g) {
                if (g < 4) {
                    uintptr_t pu = (uintptr_t)(scp + (size_t)(g + 1) * 16 * NBOX);
                    asm volatile("" : "+v"(pu) : "v"(mm));
                    const float* pl = (const float*)pu;
#pragma unroll
                    for (int u = 0; u < 16; ++u) nxt[u] = pl[(size_t)u * NBOX];
                }
#pragma unroll
                for (int u = 0; u < 16; ++u) mm = fmaxf(mm, cur[u]);
#pragma unroll
                for (int u = 0; u < 16; ++u) cur[u] = nxt[u];
            }
            m = fmaxf(mm, scp[(size_t)80 * NBOX]);
        }

        // ---- pass 2: EXACT sequential sum c=0..80 (L1/L2-hot re-read).
        // Same dep-laundered pipeline keyed on the running sum ss.
        {
            uintptr_t su = (uintptr_t)scp;
            asm volatile("" : "+v"(su) : "v"(m));
            const float* sp = (const float*)su;
            float cur[16], nxt[16];
#pragma unroll
            for (int u = 0; u < 16; ++u) cur[u] = sp[(size_t)u * NBOX];
            float ss = 0.0f;
            for (int g = 0; g < 5; ++g) {
                if (g < 4) {
                    uintptr_t pu = (uintptr_t)(sp + (size_t)(g + 1) * 16 * NBOX);
                    asm volatile("" : "+v"(pu) : "v"(ss));
                    const float* pl = (const float*)pu;
#pragma unroll
                    for (int u = 0; u < 16; ++u) nxt[u] = pl[(size_t)u * NBOX];
                }
#pragma unroll
                for (int u = 0; u < 16; ++u)
                    ss = __fadd_rn(ss, expf(__fsub_rn(cur[u], m)));
#pragma unroll
                for (int u = 0; u < 16; ++u) cur[u] = nxt[u];
            }
            ss = __fadd_rn(ss, expf(__fsub_rn(sp[(size_t)80 * NBOX], m)));
            ssum = ss;
        }
        // p > 0.05  =>  v > m + log(0.05*s); margin 1e-3 >> logf error;
        // survivors re-tested below with the exact reference expression.
        thrv = __fsub_rn(__fadd_rn(m, logf(__fmul_rn(0.05f, ssum))), 1e-3f);
    }

    // ---- pass 3: emit survivors (laundered L2-hot re-read; round-10 code)
    if (valid) {
        uintptr_t scu = (uintptr_t)scp;
        asm volatile("" : "+v"(scu) : "v"(thrv));
        const float* scv = (const float*)scu;
        for (int c0 = 1; c0 < NCLS; c0 += 16) {
            float vt[16];
#pragma unroll
            for (int u = 0; u < 16; ++u) {
                int c = c0 + u;
                vt[u] = (c < NCLS) ? scv[(size_t)c * NBOX] : -1e30f;
            }
#pragma unroll
            for (int u = 0; u < 16; ++u) {
                int c = c0 + u;
                if (vt[u] > thrv) {
                    // exact test — identical expression to validated rounds
                    float p = __fdiv_rn(expf(__fsub_rn(vt[u], m)), ssum);
                    if (p > SCORE_THR) {
                        int e = atomicAdd(&lcnt, 1);
                        if (e < LCAP) {
                            list[e] = ((unsigned long long)__float_as_uint(p) << 32) |
                                      ((unsigned long long)(unsigned)(c - 1) << 24) |
                                      (unsigned long long)(unsigned)n;
                        } else {
                            // overflow fallback (never taken on this data)
                            int pos = atomicAdd(&gcnt[b * NFG + (c - 1)], 1);
                            if (pos < GCAP)
                                gcand[(size_t)(b * NFG + (c - 1)) * GCAP + pos] =
                                    ((unsigned long long)__float_as_uint(p) << 32) |
                                    (unsigned long long)(0xFFFFFFFFu - (unsigned)n);
                        }
                    }
                }
            }
        }
    }
    __syncthreads();

    const int E = min(lcnt, LCAP);

    // ---- per-class histogram (LDS atomics)
    for (int i = tid; i < E; i += 256) {
        int c = (int)((list[i] >> 24) & 0xFF);
        atomicAdd(&ccnt[c], 1);
    }
    __syncthreads();

    // ---- one global atomic per (block, class) to reserve ranges
    if (tid < NFG && ccnt[tid] > 0)
        cbase[tid] = atomicAdd(&gcnt[b * NFG + tid], ccnt[tid]);
    __syncthreads();
    if (tid < NFG) ccnt[tid] = 0;   // reuse as cursor
    __syncthreads();

    // ---- scatter entries to reserved slots
    for (int i = tid; i < E; i += 256) {
        unsigned long long e = list[i];
        int c = (int)((e >> 24) & 0xFF);
        unsigned nn = (unsigned)(e & 0xFFFFFF);
        int pos = cbase[c] + atomicAdd(&ccnt[c], 1);
        if (pos < GCAP) {
            unsigned pb = (unsigned)(e >> 32);
            gcand[(size_t)(b * NFG + c) * GCAP + pos] =
                ((unsigned long long)pb << 32) |
                (unsigned long long)(0xFFFFFFFFu - nn);
        }
    }
}

// ---------------------------------------------------------------- register bitonic sort (NR*64 items, NR/lane, no barriers)
// Compile-time network: j>=64 -> register-pair swap; j<64 -> shfl_xor.
// All register indices are compile-time (rule #20: no scratch).
template<int NR, int J, int K>
__device__ __forceinline__ void bstep(unsigned long long (&it)[NR], const int lane) {
    if constexpr (J >= 64) {
        constexpr int M = J >> 6;
#pragma unroll
        for (int r = 0; r < NR; ++r) {
            const int rp = r ^ M;
            if (rp > r) {
                const bool desc = (((unsigned)(r << 6) & (unsigned)K) == 0u);
                unsigned long long a = it[r], bb = it[rp];
                if (desc ? (a < bb) : (a > bb)) { it[r] = bb; it[rp] = a; }
            }
        }
    } else {
#pragma unroll
        for (int r = 0; r < NR; ++r) {
            unsigned long long a = it[r];
            unsigned long long bb = __shfl_xor(a, J, 64);
            const unsigned i = ((unsigned)(r << 6)) | (unsigned)lane;
            const bool desc = ((i & (unsigned)K) == 0u);
            const bool lower = ((lane & J) == 0);
            it[r] = ((desc == lower) ? (a >= bb) : (a <= bb)) ? a : bb;
        }
    }
}

template<int NR, int K, int J>
__device__ __forceinline__ void bstage(unsigned long long (&it)[NR], const int lane) {
    bstep<NR, J, K>(it, lane);
    if constexpr (J > 1) bstage<NR, K, (J >> 1)>(it, lane);
}

template<int NR>
__device__ __forceinline__ void bsort(unsigned long long (&it)[NR], const int lane,
                                      const unsigned kmax) {
    bstage<NR, 2, 1>(it, lane);
    if (kmax >= 4)   bstage<NR, 4, 2>(it, lane);
    if (kmax >= 8)   bstage<NR, 8, 4>(it, lane);
    if (kmax >= 16)  bstage<NR, 16, 8>(it, lane);
    if (kmax >= 32)  bstage<NR, 32, 16>(it, lane);
    if (kmax >= 64)  bstage<NR, 64, 32>(it, lane);
    if constexpr (NR >= 4) {
        if (kmax >= 128) bstage<NR, 128, 64>(it, lane);
        if (kmax >= 256) bstage<NR, 256, 128>(it, lane);
    }
    if constexpr (NR >= 8)  { if (kmax >= 512)  bstage<NR, 512, 256>(it, lane); }
    if constexpr (NR >= 16) { if (kmax >= 1024) bstage<NR, 1024, 512>(it, lane); }
}

// ---------------------------------------------------------------- K2: one wave per (image,class): reg-sort + fused greedy NMS
// ROUND-7/8 LESSON: barrier-latency bound -> one wave, zero barriers.
// ROUND-9/10 LESSON: grid-limited occupancy -> cut per-wave critical path
// (cl-sized sort network; prefetch-one-row-ahead greedy NMS).
__global__ __launch_bounds__(64) void k2_nms(
    const unsigned long long* __restrict__ gcand,  // [NTASK*GCAP]
    const int* __restrict__ gcnt,                  // [NTASK]
    const float4* __restrict__ ltrb,               // [B*N]
    float* __restrict__ cls_scores,                // [NTASK*200]
    int* __restrict__ cls_idx)                     // [NTASK*200] global ltrb index
{
    const int t = blockIdx.x;       // task = b*80 + (c-1)
    const int b = t / NFG;
    const int lane = threadIdx.x;   // 0..63

    __shared__ float4 sbox[TOPK];
    __shared__ float sarea[TOPK];

    const int cl = min(gcnt[t], SORTCAP);
    const unsigned long long* gc = gcand + (size_t)t * GCAP;

    unsigned kmax = 2;
    while (kmax < (unsigned)cl) kmax <<= 1;

    // sort descending into top4 (items 0..255 = r*64+lane, r<4)
    unsigned long long top4[4];
    if (cl <= 256) {
        unsigned long long it[4];
#pragma unroll
        for (int r = 0; r < 4; ++r) {
            const int i = (r << 6) + lane;
            it[r] = (i < cl) ? gc[i] : 0ULL;
        }
        bsort<4>(it, lane, kmax);
#pragma unroll
        for (int r = 0; r < 4; ++r) top4[r] = it[r];
    } else if (cl <= 512) {
        unsigned long long it[8];
#pragma unroll
        for (int r = 0; r < 8; ++r) {
            const int i = (r << 6) + lane;
            it[r] = (i < cl) ? gc[i] : 0ULL;
        }
        bsort<8>(it, lane, kmax);
#pragma unroll
        for (int r = 0; r < 4; ++r) top4[r] = it[r];
    } else {
        unsigned long long it[16];
#pragma unroll
        for (int r = 0; r < 16; ++r) {
            const int i = (r << 6) + lane;
            it[r] = (i < cl) ? gc[i] : 0ULL;
        }
        bsort<16>(it, lane, kmax);
#pragma unroll
        for (int r = 0; r < 4; ++r) top4[r] = it[r];
    }

    const int mk = min(cl, TOPK);

    // gather top-mk boxes; lane owns items/cols i = r*64+lane, r<4
    float4 myb[4];
    float mya[4], myp[4];
    int myn[4];
#pragma unroll
    for (int r = 0; r < 4; ++r) {
        const int i = (r << 6) + lane;
        myb[r] = make_float4(0.f, 0.f, 0.f, 0.f);
        mya[r] = 0.f; myp[r] = 0.f; myn[r] = 0;
        if (i < mk) {
            const unsigned long long key = top4[r];
            const unsigned n = 0xFFFFFFFFu - (unsigned)(key & 0xFFFFFFFFull);
            const float4 bx = ltrb[(size_t)b * NBOX + n];
            myb[r] = bx;
            mya[r] = __fmul_rn(__fsub_rn(bx.z, bx.x), __fsub_rn(bx.w, bx.y));
            myp[r] = __uint_as_float((unsigned)(key >> 32));
            myn[r] = b * NBOX + (int)n;
            sbox[i] = bx;
            sarea[i] = mya[r];
        }
    }
    __syncthreads();    // 1 wave: compiles to waitcnt + immediate barrier

    // fused greedy NMS: serial over sorted i; all lanes keep identical kw
    // (ballot result is uniform). Suppressed rows cost only the bit test.
    // Row i+1's box is PREFETCHED while row i is processed.
    // IoU replicates reference's unclamped deltas; identical FP expressions.
    auto maskBits = [](int r) -> unsigned long long {
        if (r <= 0) return 0ULL;
        if (r >= 64) return ~0ULL;
        return (1ULL << r) - 1ULL;
    };
    unsigned long long kw0 = maskBits(mk);
    unsigned long long kw1 = maskBits(mk - 64);
    unsigned long long kw2 = maskBits(mk - 128);
    unsigned long long kw3 = maskBits(mk - 192);

    float4 nb = sbox[0];
    float na = sarea[0];

#define NMS_QUAD(KWQ, Q)                                                           \
    {                                                                              \
        const int i0 = (Q) << 6;                                                   \
        const int i1 = min(mk, i0 + 64);                                           \
        for (int i = i0; i < i1; ++i) {                                            \
            const float4 bi = nb;                                                  \
            const float ai = na;                                                   \
            const int ip = min(i + 1, TOPK - 1);                                   \
            nb = sbox[ip];                                                         \
            na = sarea[ip];                                                        \
            if ((KWQ >> (i - i0)) & 1ULL) {                                        \
                _Pragma("unroll")                                                  \
                for (int q2 = 0; q2 < 4; ++q2) {                                   \
                    const int j = (q2 << 6) + lane;                                \
                    const float4 bj = myb[q2];                                     \
                    const float ltx = fmaxf(bi.x, bj.x), lty = fmaxf(bi.y, bj.y);  \
                    const float rbx = fminf(bi.z, bj.z), rby = fminf(bi.w, bj.w);  \
                    const float dx = __fsub_rn(rbx, ltx), dy = __fsub_rn(rby, lty);\
                    const float inter = __fmul_rn(dx, dy);                         \
                    const float uni = __fsub_rn(__fadd_rn(ai, mya[q2]), inter);    \
                    const float iou = __fdiv_rn(inter, uni);                       \
                    const unsigned long long sup =                                 \
                        __ballot((iou >= CRITERIA) && (j > i));                    \
                    if (q2 == 0) kw0 &= ~sup;                                      \
                    else if (q2 == 1) kw1 &= ~sup;                                 \
                    else if (q2 == 2) kw2 &= ~sup;                                 \
                    else kw3 &= ~sup;                                              \
                }                                                                  \
            }                                                                      \
        }                                                                          \
    }
    NMS_QUAD(kw0, 0)
    NMS_QUAD(kw1, 1)
    NMS_QUAD(kw2, 2)
    NMS_QUAD(kw3, 3)
#undef NMS_QUAD

    // write per-class results (coalesced per r-group)
#pragma unroll
    for (int r = 0; r < 4; ++r) {
        const int i = (r << 6) + lane;
        if (i < TOPK) {
            const unsigned long long kq = (r == 0) ? kw0 : (r == 1) ? kw1
                                         : (r == 2) ? kw2 : kw3;
            const bool keep = (i < mk) && ((kq >> lane) & 1ULL);
            cls_scores[(size_t)t * TOPK + i] = keep ? myp[r] : NEG_INF;
            if (i < mk) cls_idx[(size_t)t * TOPK + i] = myn[r];
        }
    }
}

// ---------------------------------------------------------------- K3: per-image global top-200
__device__ __forceinline__ int blockReduceSum(int x, int* red, int tid) {
    __syncthreads();
    red[tid] = x;
    __syncthreads();
    for (int off = 128; off > 0; off >>= 1) {
        if (tid < off) red[tid] += red[tid + off];
        __syncthreads();
    }
    return red[0];
}

__global__ __launch_bounds__(256) void k3_topk(
    const float* __restrict__ cls_scores,   // [B*80*200]
    const int* __restrict__ cls_idx,        // [B*80*200]
    const float4* __restrict__ ltrb,        // [B*N]
    float* __restrict__ out)
{
    const int b = blockIdx.x;
    const int tid = threadIdx.x;
    const int NFLAT = NFG * TOPK;           // 16000
    const int PER = 63;

    __shared__ unsigned long long sel[512];
    __shared__ int scnt;
    __shared__ int red[256];

    const float* S = cls_scores + (size_t)b * NFLAT;
    float v[PER];
#pragma unroll
    for (int i = 0; i < PER; ++i) {
        int j = i * 256 + tid;
        v[i] = (j < NFLAT) ? S[j] : NEG_INF;
    }

    int lc = 0;
#pragma unroll
    for (int i = 0; i < PER; ++i) lc += (v[i] > -1e29f) ? 1 : 0;
    int validCount = blockReduceSum(lc, red, tid);

    unsigned thrBits = 0;
    if (validCount > TOPK) {
        unsigned lo = 0, hi = 0x7F800000u;
        while (lo < hi) {
            unsigned mid = (lo + hi) >> 1;
            float mf = __uint_as_float(mid);
            int c2 = 0;
#pragma unroll
            for (int i = 0; i < PER; ++i) c2 += (v[i] > mf) ? 1 : 0;
            int tot = blockReduceSum(c2, red, tid);
            if (tot < TOPK) hi = mid; else lo = mid + 1;
        }
        thrBits = lo;
    }

    __syncthreads();
    if (tid == 0) scnt = 0;
    for (int i = tid; i < 512; i += 256) sel[i] = 0ULL;
    __syncthreads();

    const bool useGE = (validCount > TOPK);
    const float thrF = __uint_as_float(thrBits);
#pragma unroll
    for (int i = 0; i < PER; ++i) {
        int j = i * 256 + tid;
        bool take = useGE ? (v[i] >= thrF) : (v[i] > -1e29f);
        if (j < NFLAT && take) {
            int pos = atomicAdd(&scnt, 1);
            if (pos < 512) {
                sel[pos] = ((unsigned long long)__float_as_uint(v[i]) << 32) |
                           (unsigned long long)(0xFFFFFFFFu - (unsigned)j);
            }
        }
    }
    __syncthreads();
    int total = min(min(scnt, 512), TOPK);

    for (unsigned k = 2; k <= 512; k <<= 1) {
        for (unsigned j = k >> 1; j > 0; j >>= 1) {
            for (unsigned i = tid; i < 512; i += 256) {
                unsigned ixj = i ^ j;
                if (ixj > i) {
                    unsigned long long a = sel[i], bb2 = sel[ixj];
                    bool desc = ((i & k) == 0);
                    if (desc ? (a < bb2) : (a > bb2)) { sel[i] = bb2; sel[ixj] = a; }
                }
            }
            __syncthreads();
        }
    }

    if (tid < TOPK) {
        size_t ob = (size_t)b * TOPK + tid;
        float4 bx = make_float4(0.f, 0.f, 0.f, 0.f);
        float lab = 0.f, sc2 = 0.f;
        if (tid < total) {
            unsigned long long key = sel[tid];
            unsigned j = 0xFFFFFFFFu - (unsigned)(key & 0xFFFFFFFFull);
            sc2 = __uint_as_float((unsigned)(key >> 32));
            unsigned cls = j / TOPK;
            int gi = cls_idx[(size_t)b * NFLAT + j];
            bx = ltrb[gi];
            lab = (float)(cls + 1);
        }
        reinterpret_cast<float4*>(out)[ob] = bx;
        out[(size_t)BATCH * TOPK * 4 + ob] = lab;
        out[(size_t)BATCH * TOPK * 4 + (size_t)BATCH * TOPK + ob] = sc2;
    }
}

// ---------------------------------------------------------------- launch
extern "C" void kernel_launch(void* const* d_in, const int* in_sizes, int n_in,
                              void* d_out, int out_size, void* d_ws, size_t ws_size,
                              hipStream_t stream) {
    (void)in_sizes; (void)n_in; (void)out_size; (void)ws_size;
    const float* bboxes = (const float*)d_in[0];   // [32,4,15130]
    const float* scores = (const float*)d_in[1];   // [32,81,15130]
    const float* dboxes = (const float*)d_in[2];   // [1,15130,4]
    float* out = (float*)d_out;

    char* ws = (char*)d_ws;
    size_t off = 0;
    float4* ltrb = (float4*)(ws + off);      off += (size_t)BATCH * NBOX * 16;    //  7,746,560
    unsigned long long* gcand = (unsigned long long*)(ws + off);
                                             off += (size_t)NTASK * GCAP * 8;     // 20,971,520
    float* cls_scores = (float*)(ws + off);  off += (size_t)NTASK * TOPK * 4;     //  2,048,000
    int*   cls_idx    = (int*)(ws + off);    off += (size_t)NTASK * TOPK * 4;     //  2,048,000
    int*   gcnt       = (int*)(ws + off);    off += (size_t)NTASK * 4;            //     10,240

    hipMemsetAsync(gcnt, 0, NTASK * sizeof(int), stream);

    k1_fused<<<BATCH * NCHUNK, 256, 0, stream>>>(bboxes, scores, dboxes, ltrb, gcand, gcnt);
    k2_nms<<<NTASK, 64, 0, stream>>>(gcand, gcnt, ltrb, cls_scores, cls_idx);
    k3_topk<<<BATCH, 256, 0, stream>>>(cls_scores, cls_idx, ltrb, out);
}

// Round 15
// 205.173 us; speedup vs baseline: 1.8966x; 1.1299x over previous
//
#include <hip/hip_runtime.h>
#include <cstdint>
#include <cstddef>

#define BATCH 32
#define NCLS 81
#define NFG 80
#define NBOX 15130
#define NCHUNK 60         // ceil(15130/256)
#define TOPK 200
#define NTASK (BATCH * NFG)
#define NEG_INF -1e30f
#define GCAP 1024         // per-task candidate capacity (measured mean ~434)
#define SORTCAP 1024
#define LCAP 1920         // per-chunk survivor list; measured E~590, fallback below
#define SCORE_THR 0.05f
#define CRITERIA 0.45f

// ---------------------------------------------------------------- K1: decode + softmax + compacted candidate emission
// ROUND-10..14 CONCLUSION: this exact form (1 box/thread, vals[81] with
// compiler-chosen reloads at VGPR~60) is a LOCAL OPTIMUM at ~103 us.
// Attempts that lost: launch_bounds cap (no effect), 2-box float2 (VGPR 184,
// 328 us), LDS tile via global_load_lds (occupancy 16%, 156 us), 3-pass
// dep-laundered pipeline (2.5 TB/s but +90 MB L2-thrash refetch, 113 us).
// Do not touch without a fundamentally new mechanism.
// ROUND-3 LESSON: no per-element global atomics on few hot addresses.
// ROUND-4/5/6 LESSON: k2 must read compacted lists, not re-stream scores.
__global__ __launch_bounds__(256) void k1_fused(
    const float* __restrict__ bboxes,   // [B,4,N]
    const float* __restrict__ scores,   // [B,C,N]
    const float* __restrict__ dboxes,   // [N,4]
    float4* __restrict__ ltrb,          // [B*N]
    unsigned long long* __restrict__ gcand,  // [NTASK*GCAP]
    int* __restrict__ gcnt)             // [NTASK] (zeroed before launch)
{
    const int blk = blockIdx.x;
    const int b = blk / NCHUNK;
    const int chunk = blk - b * NCHUNK;
    const int tid = threadIdx.x;
    const int n = chunk * 256 + tid;

    __shared__ unsigned long long list[LCAP];   // (p_bits<<32)|(cfg<<24)|n
    __shared__ int lcnt;
    __shared__ int ccnt[NFG];
    __shared__ int cbase[NFG];

    if (tid == 0) lcnt = 0;
    if (tid < NFG) ccnt[tid] = 0;
    __syncthreads();

    float m = 0.f, s = 1.f, thrv = 1e30f;
    const float* sc = scores;           // set properly below when n valid

    if (n < NBOX) {
        // ---- decode (bit-exact, validated rounds 1-14)
        const float* bb = bboxes + (size_t)b * 4 * NBOX + n;
        float bx = bb[0];
        float by = bb[NBOX];
        float bw = bb[2 * (size_t)NBOX];
        float bh = bb[3 * (size_t)NBOX];
        float4 d = reinterpret_cast<const float4*>(dboxes)[n];  // cx, cy, w, h
        float xx = __fadd_rn(__fmul_rn(__fmul_rn(0.1f, bx), d.z), d.x);
        float yy = __fadd_rn(__fmul_rn(__fmul_rn(0.1f, by), d.w), d.y);
        float wx = __fmul_rn(expf(__fmul_rn(0.2f, bw)), d.z);
        float wy = __fmul_rn(expf(__fmul_rn(0.2f, bh)), d.w);
        float4 o;
        o.x = __fsub_rn(xx, __fmul_rn(0.5f, wx));
        o.y = __fsub_rn(yy, __fmul_rn(0.5f, wy));
        o.z = __fadd_rn(xx, __fmul_rn(0.5f, wx));
        o.w = __fadd_rn(yy, __fmul_rn(0.5f, wy));
        ltrb[(size_t)b * NBOX + n] = o;

        // ---- softmax stats (vals[] dead after this scope; sequential sum
        // order must stay EXACT — bit-identical p has held absmax 0.0)
        sc = scores + (size_t)b * NCLS * NBOX + n;
        {
            float vals[NCLS];
#pragma unroll
            for (int c = 0; c < NCLS; ++c) vals[c] = sc[(size_t)c * NBOX];
            m = vals[0];
#pragma unroll
            for (int c = 1; c < NCLS; ++c) m = fmaxf(m, vals[c]);
            float ss = 0.0f;
#pragma unroll
            for (int c = 0; c < NCLS; ++c) ss = __fadd_rn(ss, expf(__fsub_rn(vals[c], m)));
            s = ss;
        }
        // p > 0.05  =>  v > m + log(0.05*s); margin 1e-3 >> logf error;
        // survivors re-tested below with the exact reference expression.
        thrv = __fsub_rn(__fadd_rn(m, logf(__fmul_rn(0.05f, s))), 1e-3f);
    }

    // ---- phase 3: re-read logits via laundered pointer (prevents CSE with
    // vals[]), test, emit survivors to LDS list.
    if (n < NBOX) {
        uintptr_t scu = (uintptr_t)sc;
        asm volatile("" : "+v"(scu));
        const float* scv = (const float*)scu;
        for (int c0 = 1; c0 < NCLS; c0 += 16) {
            float vt[16];
#pragma unroll
            for (int u = 0; u < 16; ++u) {
                int c = c0 + u;
                vt[u] = (c < NCLS) ? scv[(size_t)c * NBOX] : -1e30f;
            }
#pragma unroll
            for (int u = 0; u < 16; ++u) {
                int c = c0 + u;
                if (vt[u] > thrv) {
                    // exact test — identical expression to validated rounds
                    float p = __fdiv_rn(expf(__fsub_rn(vt[u], m)), s);
                    if (p > SCORE_THR) {
                        int e = atomicAdd(&lcnt, 1);
                        if (e < LCAP) {
                            list[e] = ((unsigned long long)__float_as_uint(p) << 32) |
                                      ((unsigned long long)(unsigned)(c - 1) << 24) |
                                      (unsigned long long)(unsigned)n;
                        } else {
                            // overflow fallback (never taken on this data)
                            int pos = atomicAdd(&gcnt[b * NFG + (c - 1)], 1);
                            if (pos < GCAP)
                                gcand[(size_t)(b * NFG + (c - 1)) * GCAP + pos] =
                                    ((unsigned long long)__float_as_uint(p) << 32) |
                                    (unsigned long long)(0xFFFFFFFFu - (unsigned)n);
                        }
                    }
                }
            }
        }
    }
    __syncthreads();

    const int E = min(lcnt, LCAP);

    // ---- phase 4: per-class histogram (LDS atomics)
    for (int i = tid; i < E; i += 256) {
        int c = (int)((list[i] >> 24) & 0xFF);
        atomicAdd(&ccnt[c], 1);
    }
    __syncthreads();

    // ---- phase 5: one global atomic per (block, class) to reserve ranges
    if (tid < NFG && ccnt[tid] > 0)
        cbase[tid] = atomicAdd(&gcnt[b * NFG + tid], ccnt[tid]);
    __syncthreads();
    if (tid < NFG) ccnt[tid] = 0;   // reuse as cursor
    __syncthreads();

    // ---- phase 6: scatter entries to reserved slots
    for (int i = tid; i < E; i += 256) {
        unsigned long long e = list[i];
        int c = (int)((e >> 24) & 0xFF);
        unsigned nn = (unsigned)(e & 0xFFFFFF);
        int pos = cbase[c] + atomicAdd(&ccnt[c], 1);
        if (pos < GCAP) {
            unsigned pb = (unsigned)(e >> 32);
            gcand[(size_t)(b * NFG + c) * GCAP + pos] =
                ((unsigned long long)pb << 32) |
                (unsigned long long)(0xFFFFFFFFu - nn);
        }
    }
}

// ---------------------------------------------------------------- register bitonic sort (NR*64 items, NR/lane, no barriers)
// Compile-time network: j>=64 -> register-pair swap; j<64 -> shfl_xor.
// All register indices are compile-time (rule #20: no scratch).
template<int NR, int J, int K>
__device__ __forceinline__ void bstep(unsigned long long (&it)[NR], const int lane) {
    if constexpr (J >= 64) {
        constexpr int M = J >> 6;
#pragma unroll
        for (int r = 0; r < NR; ++r) {
            const int rp = r ^ M;
            if (rp > r) {
                const bool desc = (((unsigned)(r << 6) & (unsigned)K) == 0u);
                unsigned long long a = it[r], bb = it[rp];
                if (desc ? (a < bb) : (a > bb)) { it[r] = bb; it[rp] = a; }
            }
        }
    } else {
#pragma unroll
        for (int r = 0; r < NR; ++r) {
            unsigned long long a = it[r];
            unsigned long long bb = __shfl_xor(a, J, 64);
            const unsigned i = ((unsigned)(r << 6)) | (unsigned)lane;
            const bool desc = ((i & (unsigned)K) == 0u);
            const bool lower = ((lane & J) == 0);
            it[r] = ((desc == lower) ? (a >= bb) : (a <= bb)) ? a : bb;
        }
    }
}

template<int NR, int K, int J>
__device__ __forceinline__ void bstage(unsigned long long (&it)[NR], const int lane) {
    bstep<NR, J, K>(it, lane);
    if constexpr (J > 1) bstage<NR, K, (J >> 1)>(it, lane);
}

template<int NR>
__device__ __forceinline__ void bsort(unsigned long long (&it)[NR], const int lane,
                                      const unsigned kmax) {
    bstage<NR, 2, 1>(it, lane);
    if (kmax >= 4)   bstage<NR, 4, 2>(it, lane);
    if (kmax >= 8)   bstage<NR, 8, 4>(it, lane);
    if (kmax >= 16)  bstage<NR, 16, 8>(it, lane);
    if (kmax >= 32)  bstage<NR, 32, 16>(it, lane);
    if (kmax >= 64)  bstage<NR, 64, 32>(it, lane);
    if constexpr (NR >= 4) {
        if (kmax >= 128) bstage<NR, 128, 64>(it, lane);
        if (kmax >= 256) bstage<NR, 256, 128>(it, lane);
    }
    if constexpr (NR >= 8)  { if (kmax >= 512)  bstage<NR, 512, 256>(it, lane); }
    if constexpr (NR >= 16) { if (kmax >= 1024) bstage<NR, 1024, 512>(it, lane); }
}

// ---------------------------------------------------------------- K2: one wave per (image,class): reg-sort + readlane greedy NMS
// ROUND-7/8 LESSON: barrier-latency bound -> one wave, zero barriers.
// ROUND-9/10 LESSON: grid is fixed at 2.5 waves/SIMD -> cut per-wave
// critical path. ROUND-15: the greedy loop's LDS read (~100 cyc on the
// loop-carried path per alive row, unhidden at 23% VALUBusy) is replaced
// by v_readlane broadcasts: row i's box lives in lane (i&63), reg Q
// (STATIC inside NMS_QUAD) -> 5 readlanes, SGPR results, no memory at all.
// Same FP values/order -> bit-exact. k2 now uses ZERO LDS.
__global__ __launch_bounds__(64) void k2_nms(
    const unsigned long long* __restrict__ gcand,  // [NTASK*GCAP]
    const int* __restrict__ gcnt,                  // [NTASK]
    const float4* __restrict__ ltrb,               // [B*N]
    float* __restrict__ cls_scores,                // [NTASK*200]
    int* __restrict__ cls_idx)                     // [NTASK*200] global ltrb index
{
    const int t = blockIdx.x;       // task = b*80 + (c-1)
    const int b = t / NFG;
    const int lane = threadIdx.x;   // 0..63

    const int cl = min(gcnt[t], SORTCAP);
    const unsigned long long* gc = gcand + (size_t)t * GCAP;

    unsigned kmax = 2;
    while (kmax < (unsigned)cl) kmax <<= 1;

    // sort descending into top4 (items 0..255 = r*64+lane, r<4)
    unsigned long long top4[4];
    if (cl <= 256) {
        unsigned long long it[4];
#pragma unroll
        for (int r = 0; r < 4; ++r) {
            const int i = (r << 6) + lane;
            it[r] = (i < cl) ? gc[i] : 0ULL;
        }
        bsort<4>(it, lane, kmax);
#pragma unroll
        for (int r = 0; r < 4; ++r) top4[r] = it[r];
    } else if (cl <= 512) {
        unsigned long long it[8];
#pragma unroll
        for (int r = 0; r < 8; ++r) {
            const int i = (r << 6) + lane;
            it[r] = (i < cl) ? gc[i] : 0ULL;
        }
        bsort<8>(it, lane, kmax);
#pragma unroll
        for (int r = 0; r < 4; ++r) top4[r] = it[r];
    } else {
        unsigned long long it[16];
#pragma unroll
        for (int r = 0; r < 16; ++r) {
            const int i = (r << 6) + lane;
            it[r] = (i < cl) ? gc[i] : 0ULL;
        }
        bsort<16>(it, lane, kmax);
#pragma unroll
        for (int r = 0; r < 4; ++r) top4[r] = it[r];
    }

    const int mk = min(cl, TOPK);

    // gather top-mk boxes; lane owns items/cols i = r*64+lane, r<4
    float4 myb[4];
    float mya[4], myp[4];
    int myn[4];
#pragma unroll
    for (int r = 0; r < 4; ++r) {
        const int i = (r << 6) + lane;
        myb[r] = make_float4(0.f, 0.f, 0.f, 0.f);
        mya[r] = 0.f; myp[r] = 0.f; myn[r] = 0;
        if (i < mk) {
            const unsigned long long key = top4[r];
            const unsigned n = 0xFFFFFFFFu - (unsigned)(key & 0xFFFFFFFFull);
            const float4 bx = ltrb[(size_t)b * NBOX + n];
            myb[r] = bx;
            mya[r] = __fmul_rn(__fsub_rn(bx.z, bx.x), __fsub_rn(bx.w, bx.y));
            myp[r] = __uint_as_float((unsigned)(key >> 32));
            myn[r] = b * NBOX + (int)n;
        }
    }

    // fused greedy NMS: serial over sorted i; all lanes keep identical kw
    // (ballot result is uniform). Row i's box broadcast via readlane from
    // its owning lane — zero memory traffic in the loop.
    // IoU replicates reference's unclamped deltas; identical FP expressions.
    auto maskBits = [](int r) -> unsigned long long {
        if (r <= 0) return 0ULL;
        if (r >= 64) return ~0ULL;
        return (1ULL << r) - 1ULL;
    };
    unsigned long long kw0 = maskBits(mk);
    unsigned long long kw1 = maskBits(mk - 64);
    unsigned long long kw2 = maskBits(mk - 128);
    unsigned long long kw3 = maskBits(mk - 192);

#define RDLANE_F(V, SL) __uint_as_float((unsigned)__builtin_amdgcn_readlane((int)__float_as_uint(V), (SL)))

#define NMS_QUAD(KWQ, Q)                                                           \
    {                                                                              \
        const int i0 = (Q) << 6;                                                   \
        const int i1 = min(mk, i0 + 64);                                           \
        for (int i = i0; i < i1; ++i) {                                            \
            if ((KWQ >> (i - i0)) & 1ULL) {                                        \
                const int sl = i - i0;                                             \
                const float bix = RDLANE_F(myb[Q].x, sl);                          \
                const float biy = RDLANE_F(myb[Q].y, sl);                          \
                const float biz = RDLANE_F(myb[Q].z, sl);                          \
                const float biw = RDLANE_F(myb[Q].w, sl);                          \
                const float ai  = RDLANE_F(mya[Q], sl);                            \
                _Pragma("unroll")                                                  \
                for (int q2 = 0; q2 < 4; ++q2) {                                   \
                    const int j = (q2 << 6) + lane;                                \
                    const float4 bj = myb[q2];                                     \
                    const float ltx = fmaxf(bix, bj.x), lty = fmaxf(biy, bj.y);    \
                    const float rbx = fminf(biz, bj.z), rby = fminf(biw, bj.w);    \
                    const float dx = __fsub_rn(rbx, ltx), dy = __fsub_rn(rby, lty);\
                    const float inter = __fmul_rn(dx, dy);                         \
                    const float uni = __fsub_rn(__fadd_rn(ai, mya[q2]), inter);    \
                    const float iou = __fdiv_rn(inter, uni);                       \
                    const unsigned long long sup =                                 \
                        __ballot((iou >= CRITERIA) && (j > i));                    \
                    if (q2 == 0) kw0 &= ~sup;                                      \
                    else if (q2 == 1) kw1 &= ~sup;                                 \
                    else if (q2 == 2) kw2 &= ~sup;                                 \
                    else kw3 &= ~sup;                                              \
                }                                                                  \
            }                                                                      \
        }                                                                          \
    }
    NMS_QUAD(kw0, 0)
    NMS_QUAD(kw1, 1)
    NMS_QUAD(kw2, 2)
    NMS_QUAD(kw3, 3)
#undef NMS_QUAD
#undef RDLANE_F

    // write per-class results (coalesced per r-group)
#pragma unroll
    for (int r = 0; r < 4; ++r) {
        const int i = (r << 6) + lane;
        if (i < TOPK) {
            const unsigned long long kq = (r == 0) ? kw0 : (r == 1) ? kw1
                                         : (r == 2) ? kw2 : kw3;
            const bool keep = (i < mk) && ((kq >> lane) & 1ULL);
            cls_scores[(size_t)t * TOPK + i] = keep ? myp[r] : NEG_INF;
            if (i < mk) cls_idx[(size_t)t * TOPK + i] = myn[r];
        }
    }
}

// ---------------------------------------------------------------- K3: per-image global top-200
__device__ __forceinline__ int blockReduceSum(int x, int* red, int tid) {
    __syncthreads();
    red[tid] = x;
    __syncthreads();
    for (int off = 128; off > 0; off >>= 1) {
        if (tid < off) red[tid] += red[tid + off];
        __syncthreads();
    }
    return red[0];
}

__global__ __launch_bounds__(256) void k3_topk(
    const float* __restrict__ cls_scores,   // [B*80*200]
    const int* __restrict__ cls_idx,        // [B*80*200]
    const float4* __restrict__ ltrb,        // [B*N]
    float* __restrict__ out)
{
    const int b = blockIdx.x;
    const int tid = threadIdx.x;
    const int NFLAT = NFG * TOPK;           // 16000
    const int PER = 63;

    __shared__ unsigned long long sel[512];
    __shared__ int scnt;
    __shared__ int red[256];

    const float* S = cls_scores + (size_t)b * NFLAT;
    float v[PER];
#pragma unroll
    for (int i = 0; i < PER; ++i) {
        int j = i * 256 + tid;
        v[i] = (j < NFLAT) ? S[j] : NEG_INF;
    }

    int lc = 0;
#pragma unroll
    for (int i = 0; i < PER; ++i) lc += (v[i] > -1e29f) ? 1 : 0;
    int validCount = blockReduceSum(lc, red, tid);

    unsigned thrBits = 0;
    if (validCount > TOPK) {
        unsigned lo = 0, hi = 0x7F800000u;
        while (lo < hi) {
            unsigned mid = (lo + hi) >> 1;
            float mf = __uint_as_float(mid);
            int c2 = 0;
#pragma unroll
            for (int i = 0; i < PER; ++i) c2 += (v[i] > mf) ? 1 : 0;
            int tot = blockReduceSum(c2, red, tid);
            if (tot < TOPK) hi = mid; else lo = mid + 1;
        }
        thrBits = lo;
    }

    __syncthreads();
    if (tid == 0) scnt = 0;
    for (int i = tid; i < 512; i += 256) sel[i] = 0ULL;
    __syncthreads();

    const bool useGE = (validCount > TOPK);
    const float thrF = __uint_as_float(thrBits);
#pragma unroll
    for (int i = 0; i < PER; ++i) {
        int j = i * 256 + tid;
        bool take = useGE ? (v[i] >= thrF) : (v[i] > -1e29f);
        if (j < NFLAT && take) {
            int pos = atomicAdd(&scnt, 1);
            if (pos < 512) {
                sel[pos] = ((unsigned long long)__float_as_uint(v[i]) << 32) |
                           (unsigned long long)(0xFFFFFFFFu - (unsigned)j);
            }
        }
    }
    __syncthreads();
    int total = min(min(scnt, 512), TOPK);

    for (unsigned k = 2; k <= 512; k <<= 1) {
        for (unsigned j = k >> 1; j > 0; j >>= 1) {
            for (unsigned i = tid; i < 512; i += 256) {
                unsigned ixj = i ^ j;
                if (ixj > i) {
                    unsigned long long a = sel[i], bb2 = sel[ixj];
                    bool desc = ((i & k) == 0);
                    if (desc ? (a < bb2) : (a > bb2)) { sel[i] = bb2; sel[ixj] = a; }
                }
            }
            __syncthreads();
        }
    }

    if (tid < TOPK) {
        size_t ob = (size_t)b * TOPK + tid;
        float4 bx = make_float4(0.f, 0.f, 0.f, 0.f);
        float lab = 0.f, sc2 = 0.f;
        if (tid < total) {
            unsigned long long key = sel[tid];
            unsigned j = 0xFFFFFFFFu - (unsigned)(key & 0xFFFFFFFFull);
            sc2 = __uint_as_float((unsigned)(key >> 32));
            unsigned cls = j / TOPK;
            int gi = cls_idx[(size_t)b * NFLAT + j];
            bx = ltrb[gi];
            lab = (float)(cls + 1);
        }
        reinterpret_cast<float4*>(out)[ob] = bx;
        out[(size_t)BATCH * TOPK * 4 + ob] = lab;
        out[(size_t)BATCH * TOPK * 4 + (size_t)BATCH * TOPK + ob] = sc2;
    }
}

// ---------------------------------------------------------------- launch
extern "C" void kernel_launch(void* const* d_in, const int* in_sizes, int n_in,
                              void* d_out, int out_size, void* d_ws, size_t ws_size,
                              hipStream_t stream) {
    (void)in_sizes; (void)n_in; (void)out_size; (void)ws_size;
    const float* bboxes = (const float*)d_in[0];   // [32,4,15130]
    const float* scores = (const float*)d_in[1];   // [32,81,15130]
    const float* dboxes = (const float*)d_in[2];   // [1,15130,4]
    float* out = (float*)d_out;

    char* ws = (char*)d_ws;
    size_t off = 0;
    float4* ltrb = (float4*)(ws + off);      off += (size_t)BATCH * NBOX * 16;    //  7,746,560
    unsigned long long* gcand = (unsigned long long*)(ws + off);
                                             off += (size_t)NTASK * GCAP * 8;     // 20,971,520
    float* cls_scores = (float*)(ws + off);  off += (size_t)NTASK * TOPK * 4;     //  2,048,000
    int*   cls_idx    = (int*)(ws + off);    off += (size_t)NTASK * TOPK * 4;     //  2,048,000
    int*   gcnt       = (int*)(ws + off);    off += (size_t)NTASK * 4;            //     10,240

    hipMemsetAsync(gcnt, 0, NTASK * sizeof(int), stream);

    k1_fused<<<BATCH * NCHUNK, 256, 0, stream>>>(bboxes, scores, dboxes, ltrb, gcand, gcnt);
    k2_nms<<<NTASK, 64, 0, stream>>>(gcand, gcnt, ltrb, cls_scores, cls_idx);
    k3_topk<<<BATCH, 256, 0, stream>>>(cls_scores, cls_idx, ltrb, out);
}